// Round 12
// baseline (135.585 us; speedup 1.0000x reference)
//
#include <hip/hip_runtime.h>
#include <hip/hip_bf16.h>

// ---------------------------------------------------------------------------
// MHSA: x[2,2048,1024] f32, Wq/Wk/Wv/Wo[1024,1024] f32 -> out[2,2048,1024] f32.
// Internal bf16. Pipeline:
//   1) convert: x -> xb (bf16 in d_out[0:8MB]); W* -> wb (ws); init work counter
//   2) fused QKV GEMM: BK=64, XOR-swizzled global_load_lds staging.
//   3) causal flash attention: round-9 block structure (2 waves / 64 q-rows,
//      KV-64 dbuf, counted vmcnt(8)) + DYNAMIC WORK STEALING: 1024 items
//      (qt,bh); items 0..511 (heavy, qt>=16) static to blocks 0..511;
//      items 512..1023 popped via device-scope atomic (LPT balancing).
//   4) Wo GEMM 64x128 tiles (512 blocks = 2/CU) -> f32 d_out
// ws (shorts): wb[4x1M] Q[4M] K[4M] VtG[4M] = 32 MB. attn out aliases Q.
// Work counter: d_out + 12MB (dead until Wo GEMM overwrites d_out).
// ---------------------------------------------------------------------------

#define DEVI __device__ __forceinline__

typedef __bf16 bf16x8 __attribute__((ext_vector_type(8)));
typedef short  short8 __attribute__((ext_vector_type(8)));
typedef float  f32x4  __attribute__((ext_vector_type(4)));
typedef float  f32x16 __attribute__((ext_vector_type(16)));
typedef unsigned int u32x4 __attribute__((ext_vector_type(4)));

DEVI short f2bfs(float f) {
    __hip_bfloat16 h = __float2bfloat16(f);
    return __builtin_bit_cast(short, h);
}
DEVI unsigned pack2(float a, float b) {
    return (unsigned)(unsigned short)f2bfs(a) | ((unsigned)(unsigned short)f2bfs(b) << 16);
}
DEVI bf16x8 ld8(const short* p) {
    return __builtin_bit_cast(bf16x8, *(const short8*)p);
}
DEVI void gload16(const void* g, void* lds) {
    __builtin_amdgcn_global_load_lds(
        (const __attribute__((address_space(1))) void*)g,
        (__attribute__((address_space(3))) void*)lds, 16, 0, 0);
}
// XOR-swizzled LDS read address for [64][64] bf16 tiles (involution on the
// 16B slot index within each 128B row): byte ^= (row&7)<<4.
DEVI const short* lds_swc(const short* base, int row, int col) {
    return (const short*)((const char*)base + (((row << 7) + (col << 1)) ^ ((row & 7) << 4)));
}

#if defined(__has_builtin)
#if __has_builtin(__builtin_amdgcn_exp2f)
#define HAVE_EXP2 1
#endif
#endif
DEVI float ex2(float x) {
#ifdef HAVE_EXP2
    return __builtin_amdgcn_exp2f(x);
#else
    return __expf(x * 0.69314718055994531f);
#endif
}
// 0.125 (1/sqrt(64)) folded with log2(e): p = 2^((s - m) * CEXP)
#define CEXP 0.18033688011112042f

// ---------------------------------------------------------------------------
// f32 -> bf16 convert, 1-D exact grid. Also re-inits the attn work counter.
// ---------------------------------------------------------------------------
__global__ __launch_bounds__(256) void convert_kernel(
    const float* __restrict__ x, const float* __restrict__ Wq,
    const float* __restrict__ Wk, const float* __restrict__ Wv,
    const float* __restrict__ Wo, short* __restrict__ xb, short* __restrict__ wb,
    int* __restrict__ cnt) {
    const int bid = blockIdx.x;
    if (bid == 0 && threadIdx.x == 0) *cnt = 512;   // items 512..1023 dynamic
    const float* src;
    short* dst;
    int i8;
    if (bid < 2048) {
        src = x; dst = xb;
        i8 = (bid * 256 + threadIdx.x) * 8;
    } else {
        const int w = bid - 2048;
        const int z = w >> 9;                  // 0..3
        src = (z == 0) ? Wq : (z == 1) ? Wk : (z == 2) ? Wv : Wo;
        dst = wb + (size_t)z * 1048576;
        i8 = (((w & 511) * 256) + threadIdx.x) * 8;
    }
    float4 a = ((const float4*)(src + i8))[0];
    float4 b = ((const float4*)(src + i8))[1];
    short8 t;
    t[0] = f2bfs(a.x); t[1] = f2bfs(a.y); t[2] = f2bfs(a.z); t[3] = f2bfs(a.w);
    t[4] = f2bfs(b.x); t[5] = f2bfs(b.y); t[6] = f2bfs(b.z); t[7] = f2bfs(b.w);
    *(short8*)(dst + i8) = t;
}

// ---------------------------------------------------------------------------
// bf16 NT-GEMM K-loop, BK=64, XOR-swizzled staging (conflict-free reads).
// Template: <BM, BN, MF, NF, WN>.  4 waves; wm = wid/WN, wn = wid%WN.
// ---------------------------------------------------------------------------
template <int BM, int BN, int MF, int NF, int WN>
DEVI void gemm_kloop64(const short* __restrict__ A, const short* __restrict__ B,
                       short* As, short* Bs, int wid, int lane, f32x4 acc[MF][NF]) {
    const int l15 = lane & 15, l4 = lane >> 4;
    const int wm = wid / WN, wn = wid % WN;
    const int rowc = lane >> 3;                 // 0..7: row within 8-row chunk
    const int gcol = ((lane & 7) ^ rowc) * 8;   // pre-swizzled 16B slot
    constexpr int NCHA = BM / 8, NCHB = BN / 8;
#pragma unroll 1
    for (int k0 = 0; k0 < 1024; k0 += 64) {
        __syncthreads();
#pragma unroll
        for (int c = wid; c < NCHA; c += 4)
            gload16(A + (size_t)(c * 8 + rowc) * 1024 + k0 + gcol, As + c * 512);
#pragma unroll
        for (int c = wid; c < NCHB; c += 4)
            gload16(B + (size_t)(c * 8 + rowc) * 1024 + k0 + gcol, Bs + c * 512);
        __syncthreads();
#pragma unroll
        for (int kk = 0; kk < 2; ++kk) {
            bf16x8 af[MF], bf[NF];
#pragma unroll
            for (int m = 0; m < MF; ++m) {
                const int row = wm * (MF * 16) + m * 16 + l15;
                af[m] = ld8(As + row * 64 + (((kk * 4 + l4) ^ (row & 7)) * 8));
            }
#pragma unroll
            for (int n = 0; n < NF; ++n) {
                const int row = wn * (NF * 16) + n * 16 + l15;
                bf[n] = ld8(Bs + row * 64 + (((kk * 4 + l4) ^ (row & 7)) * 8));
            }
#pragma unroll
            for (int m = 0; m < MF; ++m)
#pragma unroll
                for (int n = 0; n < NF; ++n)
                    acc[m][n] = __builtin_amdgcn_mfma_f32_16x16x32_bf16(af[m], bf[n], acc[m][n], 0, 0, 0);
        }
    }
}

// ---------------------------------------------------------------------------
// Fused QKV projection. grid (32, 24): y>>3 selects weight; (y&7) col tile.
// ---------------------------------------------------------------------------
__global__ __launch_bounds__(256) void gemm_qkv_kernel(
    const short* __restrict__ xb, const short* __restrict__ wb,
    short* __restrict__ Qo, short* __restrict__ Ko, short* __restrict__ VtG) {
    __shared__ short As[8192], Bs[8192];
    const int tid = threadIdx.x, lane = tid & 63, wid = tid >> 6;
    const int l15 = lane & 15, l4 = lane >> 4;
    const int wm = wid >> 1, wn = wid & 1;
    const int y = blockIdx.y, wsel = y >> 3;
    const int row0 = blockIdx.x * 128, col0 = (y & 7) * 128;

    f32x4 acc[4][4] = {};
    gemm_kloop64<128, 128, 4, 4, 2>(
        xb + (size_t)row0 * 1024,
        wb + (size_t)wsel * 1048576 + (size_t)col0 * 1024,
        As, Bs, wid, lane, acc);

    if (wsel == 2) {
#pragma unroll
        for (int m = 0; m < 4; ++m)
#pragma unroll
            for (int n = 0; n < 4; ++n)
#pragma unroll
                for (int j = 0; j < 4; ++j) {
                    int row = row0 + wm * 64 + m * 16 + l4 * 4 + j;
                    int col = col0 + wn * 64 + n * 16 + l15;
                    VtG[(size_t)col * 4096 + row] = f2bfs(acc[m][n][j]);
                }
    } else {
        short* C = (wsel == 0) ? Qo : Ko;
#pragma unroll
        for (int m = 0; m < 4; ++m)
#pragma unroll
            for (int n = 0; n < 4; ++n)
#pragma unroll
                for (int j = 0; j < 4; ++j) {
                    int row = row0 + wm * 64 + m * 16 + l4 * 4 + j;
                    int col = col0 + wn * 64 + n * 16 + l15;
                    C[(size_t)row * 1024 + col] = f2bfs(acc[m][n][j]);
                }
    }
}

// ---------------------------------------------------------------------------
// Output projection: 64x128 tile (512 blocks = 2/CU), BK=64. Waves 1x4.
// ---------------------------------------------------------------------------
__global__ __launch_bounds__(256) void gemm_wo_kernel(
    const short* __restrict__ Ao, const short* __restrict__ Wob,
    float* __restrict__ Cout) {
    __shared__ short As[4096], Bs[8192];
    const int tid = threadIdx.x, lane = tid & 63, wid = tid >> 6;
    const int l15 = lane & 15, l4 = lane >> 4;
    const int wn = wid;                       // WN=4: wm = 0
    const int row0 = blockIdx.x * 64, col0 = blockIdx.y * 128;

    f32x4 acc[4][2] = {};
    gemm_kloop64<64, 128, 4, 2, 4>(
        Ao + (size_t)row0 * 1024, Wob + (size_t)col0 * 1024,
        As, Bs, wid, lane, acc);

#pragma unroll
    for (int m = 0; m < 4; ++m)
#pragma unroll
        for (int n = 0; n < 2; ++n)
#pragma unroll
            for (int j = 0; j < 4; ++j) {
                int row = row0 + m * 16 + l4 * 4 + j;
                int col = col0 + wn * 32 + n * 16 + l15;
                Cout[(size_t)row * 1024 + col] = acc[m][n][j];
            }
}

// ---------------------------------------------------------------------------
// One KV tile (verified rounds 4-11): S = K Q^T, exp2-domain online softmax,
// defer-max, shfl_xor(32) P-redistribute, O += P V.
// ---------------------------------------------------------------------------
DEVI void attn_tile(int kv0, bool diag, const short* Ks, const short* Vts,
                    const bf16x8 qf[4], f32x16& o0, f32x16& o1,
                    float& m, float& l, int qrow, int l31, int hi) {
    f32x16 s0 = 0.0f, s1 = 0.0f;
    __builtin_amdgcn_s_setprio(1);
#pragma unroll
    for (int ds = 0; ds < 4; ++ds) {
        bf16x8 kf = ld8(lds_swc(Ks, l31, ds * 16 + hi * 8));
        s0 = __builtin_amdgcn_mfma_f32_32x32x16_bf16(kf, qf[ds], s0, 0, 0, 0);
    }
#pragma unroll
    for (int ds = 0; ds < 4; ++ds) {
        bf16x8 kf = ld8(lds_swc(Ks, 32 + l31, ds * 16 + hi * 8));
        s1 = __builtin_amdgcn_mfma_f32_32x32x16_bf16(kf, qf[ds], s1, 0, 0, 0);
    }
    __builtin_amdgcn_s_setprio(0);

    if (diag) {
#pragma unroll
        for (int r = 0; r < 16; ++r) {
            const int kvr = kv0 + (r & 3) + 8 * (r >> 2) + 4 * hi;
            if (kvr > qrow)      s0[r] = -3.0e38f;
            if (kvr + 32 > qrow) s1[r] = -3.0e38f;
        }
    }
    float mx0 = -3.0e38f, mx1 = -3.0e38f, mx2 = -3.0e38f, mx3 = -3.0e38f;
#pragma unroll
    for (int r = 0; r < 16; r += 4) {
        mx0 = fmaxf(mx0, fmaxf(s0[r],     s1[r]));
        mx1 = fmaxf(mx1, fmaxf(s0[r + 1], s1[r + 1]));
        mx2 = fmaxf(mx2, fmaxf(s0[r + 2], s1[r + 2]));
        mx3 = fmaxf(mx3, fmaxf(s0[r + 3], s1[r + 3]));
    }
    float pmax = fmaxf(fmaxf(mx0, mx1), fmaxf(mx2, mx3));
    pmax = fmaxf(pmax, __shfl_xor(pmax, 32, 64));

    if (__any(pmax > m + 64.0f)) {
        const float mnew = fmaxf(m, pmax);
        const float corr = ex2((m - mnew) * CEXP);
        m = mnew;
        l *= corr;
#pragma unroll
        for (int r = 0; r < 16; ++r) {
            const int cr = (r & 3) + 8 * (r >> 2) + 4 * hi;
            const float c = __shfl(corr, cr, 64);
            o0[r] *= c; o1[r] *= c;
        }
    }

    const float mc = m * CEXP;
    float r0 = 0.f, r1 = 0.f, r2 = 0.f, r3 = 0.f;
    unsigned w0[8], w1[8];
#pragma unroll
    for (int i = 0; i < 8; ++i) {
        const float p0 = ex2(__builtin_fmaf(s0[2 * i],     CEXP, -mc));
        const float p1 = ex2(__builtin_fmaf(s0[2 * i + 1], CEXP, -mc));
        const float p2 = ex2(__builtin_fmaf(s1[2 * i],     CEXP, -mc));
        const float p3 = ex2(__builtin_fmaf(s1[2 * i + 1], CEXP, -mc));
        r0 += p0; r1 += p1; r2 += p2; r3 += p3;
        w0[i] = pack2(p0, p1);
        w1[i] = pack2(p2, p3);
    }
    const float rsum = (r0 + r1) + (r2 + r3);
    l += rsum + __shfl_xor(rsum, 32, 64);

    __builtin_amdgcn_s_setprio(1);
#pragma unroll
    for (int c = 0; c < 2; ++c) {
        const unsigned* w = (c == 0) ? w0 : w1;
        unsigned pw[8];
#pragma unroll
        for (int i = 0; i < 8; ++i) pw[i] = __shfl_xor(w[i], 32, 64);
        u32x4 lo, hw;
        lo[0] = hi ? pw[2] : w[0];  lo[1] = hi ? pw[3] : w[1];
        lo[2] = hi ? w[2]  : pw[0]; lo[3] = hi ? w[3]  : pw[1];
        hw[0] = hi ? pw[6] : w[4];  hw[1] = hi ? pw[7] : w[5];
        hw[2] = hi ? w[6]  : pw[4]; hw[3] = hi ? w[7]  : pw[5];
        const bf16x8 paL = __builtin_bit_cast(bf16x8, lo);
        const bf16x8 paH = __builtin_bit_cast(bf16x8, hw);

        bf16x8 vb;
        vb = ld8(lds_swc(Vts, l31,      c * 32 + hi * 8));
        o0 = __builtin_amdgcn_mfma_f32_32x32x16_bf16(paL, vb, o0, 0, 0, 0);
        vb = ld8(lds_swc(Vts, 32 + l31, c * 32 + hi * 8));
        o1 = __builtin_amdgcn_mfma_f32_32x32x16_bf16(paL, vb, o1, 0, 0, 0);
        vb = ld8(lds_swc(Vts, l31,      c * 32 + 16 + hi * 8));
        o0 = __builtin_amdgcn_mfma_f32_32x32x16_bf16(paH, vb, o0, 0, 0, 0);
        vb = ld8(lds_swc(Vts, 32 + l31, c * 32 + 16 + hi * 8));
        o1 = __builtin_amdgcn_mfma_f32_32x32x16_bf16(paH, vb, o1, 0, 0, 0);
    }
    __builtin_amdgcn_s_setprio(0);
}

// ---------------------------------------------------------------------------
// Causal flash attention with dynamic work stealing.
// 1024 items: item -> qt = 31 - item/32 (heavy first), bh = item&31.
// grid 1024 x 128 (2 waves, 64 q-rows, KV-64 dbuf, counted vmcnt(8)).
// Blocks 0..511 start on items 0..511 (qt 31..16, the 17..32-tile monsters);
// everyone then pops items from a device-scope atomic counter (starts at 512)
// until the queue (items 512..1023, qt 15..0) is exhausted -> LPT balancing
// without assuming anything about block->CU placement.
// ---------------------------------------------------------------------------
__global__ __launch_bounds__(128) void attn_kernel(
    const short* __restrict__ Q, const short* __restrict__ K,
    const short* __restrict__ VtG, short* __restrict__ O,
    int* __restrict__ cnt) {
    __shared__ short KsA[4096], VtsA[4096], KsB[4096], VtsB[4096];
    __shared__ int itemSh;

    const int tid = threadIdx.x, lane = tid & 63, wid = tid >> 6;
    const int l31 = lane & 31, hi = lane >> 5;
    const int srw = lane >> 3;                 // 0..7
    const int swc = ((lane & 7) ^ srw) * 8;    // swizzled col (elements)
    const int cc0 = wid * 4;

    int item;
    if (blockIdx.x < 512) {
        item = blockIdx.x;
    } else {
        if (tid == 0) itemSh = atomicAdd(cnt, 1);
        __syncthreads();
        item = itemSh;
    }

#pragma unroll 1
    while (item < 1024) {
        const int qt = 31 - (item >> 5);
        const int bh = item & 31;
        const int b = bh >> 4, h = bh & 15;
        const size_t base = (size_t)b * 2048 * 1024 + (size_t)h * 64;
        const short* Qp = Q + base;
        const short* Kp = K + base;
        const short* Vp = VtG + (size_t)(h * 64) * 4096 + (size_t)b * 2048;
        short* Op = O + base;

        const int q0w = qt * 64 + wid * 32;
        const int qrow = q0w + l31;
        const short* kSrc = Kp + (size_t)srw * 1024 + swc;
        const short* vSrc = Vp + (size_t)srw * 4096 + swc;

#define ISSUE_TILE(Ksb, Vtsb, kv0_)                                           \
    {                                                                         \
        const int kv0i = (kv0_);                                              \
        _Pragma("unroll")                                                     \
        for (int c = 0; c < 4; ++c) {                                         \
            const int cc = cc0 + c;                                           \
            gload16(kSrc + (size_t)(kv0i + cc * 8) * 1024, (Ksb) + cc * 512); \
            gload16(vSrc + (size_t)(cc * 8) * 4096 + kv0i, (Vtsb) + cc * 512);\
        }                                                                     \
    }

        ISSUE_TILE(KsA, VtsA, 0);

        bf16x8 qf[4];
#pragma unroll
        for (int ds = 0; ds < 4; ++ds)
            qf[ds] = ld8(Qp + (size_t)qrow * 1024 + ds * 16 + hi * 8);

        f32x16 o0 = 0.0f, o1 = 0.0f;
        float m = -INFINITY, l = 0.0f;
        const int ntiles = qt + 1;

#pragma unroll 1
        for (int t = 0; t < ntiles; ++t) {
            const short* Ks  = (t & 1) ? KsB  : KsA;
            const short* Vts = (t & 1) ? VtsB : VtsA;
            if (t + 1 < ntiles) {
                short* Ksn  = (t & 1) ? KsA  : KsB;
                short* Vtsn = (t & 1) ? VtsA : VtsB;
                ISSUE_TILE(Ksn, Vtsn, (t + 1) * 64);
                asm volatile("s_waitcnt vmcnt(8)" ::: "memory");
            } else {
                asm volatile("s_waitcnt vmcnt(0)" ::: "memory");
            }
            __builtin_amdgcn_s_barrier();
            __builtin_amdgcn_sched_barrier(0);
            attn_tile(t * 64, (t * 64 + 63 > q0w), Ks, Vts, qf, o0, o1, m, l, qrow, l31, hi);
            __builtin_amdgcn_s_barrier();
        }
#undef ISSUE_TILE

        const float il = 1.0f / l;
#pragma unroll
        for (int r = 0; r < 16; ++r) {
            const int cr = (r & 3) + 8 * (r >> 2) + 4 * hi;
            const float s = __shfl(il, cr, 64);
            const size_t row = (size_t)(q0w + cr) * 1024;
            Op[row + l31]      = f2bfs(o0[r] * s);
            Op[row + 32 + l31] = f2bfs(o1[r] * s);
        }

        // pop next item (both waves agree via LDS broadcast; the barrier also
        // guards LDS tile reuse across items)
        if (tid == 0) itemSh = atomicAdd(cnt, 1);
        __syncthreads();
        item = itemSh;
    }
}

// ---------------------------------------------------------------------------
extern "C" void kernel_launch(void* const* d_in, const int* in_sizes, int n_in,
                              void* d_out, int out_size, void* d_ws, size_t ws_size,
                              hipStream_t stream) {
    const float* x  = (const float*)d_in[0];
    const float* Wq = (const float*)d_in[1];
    const float* Wk = (const float*)d_in[2];
    const float* Wv = (const float*)d_in[3];
    const float* Wo = (const float*)d_in[4];

    short* wb  = (short*)d_ws;                 // 4 x 1M shorts (8 MB)
    short* Qw  = wb + (size_t)4 * 1048576;     // 8 MB (attn out aliases this)
    short* Kw  = Qw + (size_t)4194304;         // 8 MB
    short* Vtw = Kw + (size_t)4194304;         // 8 MB  (VtG[1024][4096])
    short* xb  = (short*)d_out;                // bf16 x lives in d_out[0:8MB]
    int*   cnt = (int*)((char*)d_out + (size_t)12 * 1024 * 1024);  // dead zone

    convert_kernel<<<4096, 256, 0, stream>>>(x, Wq, Wk, Wv, Wo, xb, wb, cnt);
    gemm_qkv_kernel<<<dim3(32, 24), 256, 0, stream>>>(xb, wb, Qw, Kw, Vtw);
    attn_kernel<<<1024, 128, 0, stream>>>(Qw, Kw, Vtw, Qw, cnt);
    gemm_wo_kernel<<<dim3(64, 8), 256, 0, stream>>>(Qw, wb + (size_t)3 * 1048576, (float*)d_out);
}

// Round 13
// 122.993 us; speedup vs baseline: 1.1024x; 1.1024x over previous
//
#include <hip/hip_runtime.h>
#include <hip/hip_bf16.h>

// ---------------------------------------------------------------------------
// MHSA: x[2,2048,1024] f32, Wq/Wk/Wv/Wo[1024,1024] f32 -> out[2,2048,1024] f32.
// Internal bf16. Pipeline (round-9 structure + permlane32_swap redistribute):
//   1) convert: x -> xb (bf16 in d_out[0:8MB]); W* -> wb (ws)
//   2) fused QKV GEMM: BK=64, XOR-swizzled global_load_lds staging.
//   3) causal flash attention: 2 waves / 64 q-rows, KV-64 dbuf, counted
//      vmcnt(8), heavy-first static grid; P-redistribute via
//      v_permlane32_swap_b32 (replaces 16 bpermute + 32 cndmask per tile).
//   4) Wo GEMM 64x128 tiles (512 blocks = 2/CU) -> f32 d_out
// ws (shorts): wb[4x1M] Q[4M] K[4M] VtG[4M] = 32 MB. attn out aliases Q.
// ---------------------------------------------------------------------------

#define DEVI __device__ __forceinline__

typedef __bf16 bf16x8 __attribute__((ext_vector_type(8)));
typedef short  short8 __attribute__((ext_vector_type(8)));
typedef float  f32x4  __attribute__((ext_vector_type(4)));
typedef float  f32x16 __attribute__((ext_vector_type(16)));
typedef unsigned int u32x4 __attribute__((ext_vector_type(4)));

DEVI short f2bfs(float f) {
    __hip_bfloat16 h = __float2bfloat16(f);
    return __builtin_bit_cast(short, h);
}
DEVI unsigned pack2(float a, float b) {
    return (unsigned)(unsigned short)f2bfs(a) | ((unsigned)(unsigned short)f2bfs(b) << 16);
}
DEVI bf16x8 ld8(const short* p) {
    return __builtin_bit_cast(bf16x8, *(const short8*)p);
}
DEVI void gload16(const void* g, void* lds) {
    __builtin_amdgcn_global_load_lds(
        (const __attribute__((address_space(1))) void*)g,
        (__attribute__((address_space(3))) void*)lds, 16, 0, 0);
}
// v_permlane32_swap_b32: a.hi <-> b.lo  =>  a' = {a.lo, b.lo}, b' = {a.hi, b.hi}
DEVI void plswap(unsigned& a, unsigned& b) {
    asm volatile("v_permlane32_swap_b32 %0, %1" : "+v"(a), "+v"(b));
}
// XOR-swizzled LDS read address for [64][64] bf16 tiles (involution on the
// 16B slot index within each 128B row): byte ^= (row&7)<<4.
DEVI const short* lds_swc(const short* base, int row, int col) {
    return (const short*)((const char*)base + (((row << 7) + (col << 1)) ^ ((row & 7) << 4)));
}

#if defined(__has_builtin)
#if __has_builtin(__builtin_amdgcn_exp2f)
#define HAVE_EXP2 1
#endif
#endif
DEVI float ex2(float x) {
#ifdef HAVE_EXP2
    return __builtin_amdgcn_exp2f(x);
#else
    return __expf(x * 0.69314718055994531f);
#endif
}
// 0.125 (1/sqrt(64)) folded with log2(e): p = 2^((s - m) * CEXP)
#define CEXP 0.18033688011112042f

// ---------------------------------------------------------------------------
// f32 -> bf16 convert, 1-D exact grid.
// ---------------------------------------------------------------------------
__global__ __launch_bounds__(256) void convert_kernel(
    const float* __restrict__ x, const float* __restrict__ Wq,
    const float* __restrict__ Wk, const float* __restrict__ Wv,
    const float* __restrict__ Wo, short* __restrict__ xb, short* __restrict__ wb) {
    const int bid = blockIdx.x;
    const float* src;
    short* dst;
    int i8;
    if (bid < 2048) {
        src = x; dst = xb;
        i8 = (bid * 256 + threadIdx.x) * 8;
    } else {
        const int w = bid - 2048;
        const int z = w >> 9;                  // 0..3
        src = (z == 0) ? Wq : (z == 1) ? Wk : (z == 2) ? Wv : Wo;
        dst = wb + (size_t)z * 1048576;
        i8 = (((w & 511) * 256) + threadIdx.x) * 8;
    }
    float4 a = ((const float4*)(src + i8))[0];
    float4 b = ((const float4*)(src + i8))[1];
    short8 t;
    t[0] = f2bfs(a.x); t[1] = f2bfs(a.y); t[2] = f2bfs(a.z); t[3] = f2bfs(a.w);
    t[4] = f2bfs(b.x); t[5] = f2bfs(b.y); t[6] = f2bfs(b.z); t[7] = f2bfs(b.w);
    *(short8*)(dst + i8) = t;
}

// ---------------------------------------------------------------------------
// bf16 NT-GEMM K-loop, BK=64, XOR-swizzled staging (conflict-free reads).
// Template: <BM, BN, MF, NF, WN>.  4 waves; wm = wid/WN, wn = wid%WN.
// ---------------------------------------------------------------------------
template <int BM, int BN, int MF, int NF, int WN>
DEVI void gemm_kloop64(const short* __restrict__ A, const short* __restrict__ B,
                       short* As, short* Bs, int wid, int lane, f32x4 acc[MF][NF]) {
    const int l15 = lane & 15, l4 = lane >> 4;
    const int wm = wid / WN, wn = wid % WN;
    const int rowc = lane >> 3;                 // 0..7: row within 8-row chunk
    const int gcol = ((lane & 7) ^ rowc) * 8;   // pre-swizzled 16B slot
    constexpr int NCHA = BM / 8, NCHB = BN / 8;
#pragma unroll 1
    for (int k0 = 0; k0 < 1024; k0 += 64) {
        __syncthreads();
#pragma unroll
        for (int c = wid; c < NCHA; c += 4)
            gload16(A + (size_t)(c * 8 + rowc) * 1024 + k0 + gcol, As + c * 512);
#pragma unroll
        for (int c = wid; c < NCHB; c += 4)
            gload16(B + (size_t)(c * 8 + rowc) * 1024 + k0 + gcol, Bs + c * 512);
        __syncthreads();
#pragma unroll
        for (int kk = 0; kk < 2; ++kk) {
            bf16x8 af[MF], bf[NF];
#pragma unroll
            for (int m = 0; m < MF; ++m) {
                const int row = wm * (MF * 16) + m * 16 + l15;
                af[m] = ld8(As + row * 64 + (((kk * 4 + l4) ^ (row & 7)) * 8));
            }
#pragma unroll
            for (int n = 0; n < NF; ++n) {
                const int row = wn * (NF * 16) + n * 16 + l15;
                bf[n] = ld8(Bs + row * 64 + (((kk * 4 + l4) ^ (row & 7)) * 8));
            }
#pragma unroll
            for (int m = 0; m < MF; ++m)
#pragma unroll
                for (int n = 0; n < NF; ++n)
                    acc[m][n] = __builtin_amdgcn_mfma_f32_16x16x32_bf16(af[m], bf[n], acc[m][n], 0, 0, 0);
        }
    }
}

// ---------------------------------------------------------------------------
// Fused QKV projection. grid (32, 24): y>>3 selects weight; (y&7) col tile.
// ---------------------------------------------------------------------------
__global__ __launch_bounds__(256) void gemm_qkv_kernel(
    const short* __restrict__ xb, const short* __restrict__ wb,
    short* __restrict__ Qo, short* __restrict__ Ko, short* __restrict__ VtG) {
    __shared__ short As[8192], Bs[8192];
    const int tid = threadIdx.x, lane = tid & 63, wid = tid >> 6;
    const int l15 = lane & 15, l4 = lane >> 4;
    const int wm = wid >> 1, wn = wid & 1;
    const int y = blockIdx.y, wsel = y >> 3;
    const int row0 = blockIdx.x * 128, col0 = (y & 7) * 128;

    f32x4 acc[4][4] = {};
    gemm_kloop64<128, 128, 4, 4, 2>(
        xb + (size_t)row0 * 1024,
        wb + (size_t)wsel * 1048576 + (size_t)col0 * 1024,
        As, Bs, wid, lane, acc);

    if (wsel == 2) {
#pragma unroll
        for (int m = 0; m < 4; ++m)
#pragma unroll
            for (int n = 0; n < 4; ++n)
#pragma unroll
                for (int j = 0; j < 4; ++j) {
                    int row = row0 + wm * 64 + m * 16 + l4 * 4 + j;
                    int col = col0 + wn * 64 + n * 16 + l15;
                    VtG[(size_t)col * 4096 + row] = f2bfs(acc[m][n][j]);
                }
    } else {
        short* C = (wsel == 0) ? Qo : Ko;
#pragma unroll
        for (int m = 0; m < 4; ++m)
#pragma unroll
            for (int n = 0; n < 4; ++n)
#pragma unroll
                for (int j = 0; j < 4; ++j) {
                    int row = row0 + wm * 64 + m * 16 + l4 * 4 + j;
                    int col = col0 + wn * 64 + n * 16 + l15;
                    C[(size_t)row * 1024 + col] = f2bfs(acc[m][n][j]);
                }
    }
}

// ---------------------------------------------------------------------------
// Output projection: 64x128 tile (512 blocks = 2/CU), BK=64. Waves 1x4.
// ---------------------------------------------------------------------------
__global__ __launch_bounds__(256) void gemm_wo_kernel(
    const short* __restrict__ Ao, const short* __restrict__ Wob,
    float* __restrict__ Cout) {
    __shared__ short As[4096], Bs[8192];
    const int tid = threadIdx.x, lane = tid & 63, wid = tid >> 6;
    const int l15 = lane & 15, l4 = lane >> 4;
    const int wn = wid;                       // WN=4: wm = 0
    const int row0 = blockIdx.x * 64, col0 = blockIdx.y * 128;

    f32x4 acc[4][2] = {};
    gemm_kloop64<64, 128, 4, 2, 4>(
        Ao + (size_t)row0 * 1024, Wob + (size_t)col0 * 1024,
        As, Bs, wid, lane, acc);

#pragma unroll
    for (int m = 0; m < 4; ++m)
#pragma unroll
        for (int n = 0; n < 2; ++n)
#pragma unroll
            for (int j = 0; j < 4; ++j) {
                int row = row0 + m * 16 + l4 * 4 + j;
                int col = col0 + wn * 32 + n * 16 + l15;
                Cout[(size_t)row * 1024 + col] = acc[m][n][j];
            }
}

// ---------------------------------------------------------------------------
// One KV tile: S = K Q^T, exp2-domain online softmax, defer-max,
// permlane32_swap P-redistribute (replaces shfl_xor + cndmask), O += P V.
// Mapping check (vs verified hi?pw:w table):
//   lo[0] = hi? pw[2]:w[0] = {w0.lo,w2.lo} = swap(w0,w2).first
//   lo[2] = hi? w[2]:pw[0] = {w0.hi,w2.hi} = swap(w0,w2).second   (etc.)
// ---------------------------------------------------------------------------
DEVI void attn_tile(int kv0, bool diag, const short* Ks, const short* Vts,
                    const bf16x8 qf[4], f32x16& o0, f32x16& o1,
                    float& m, float& l, int qrow, int l31, int hi) {
    f32x16 s0 = 0.0f, s1 = 0.0f;
    __builtin_amdgcn_s_setprio(1);
#pragma unroll
    for (int ds = 0; ds < 4; ++ds) {
        bf16x8 kf = ld8(lds_swc(Ks, l31, ds * 16 + hi * 8));
        s0 = __builtin_amdgcn_mfma_f32_32x32x16_bf16(kf, qf[ds], s0, 0, 0, 0);
    }
#pragma unroll
    for (int ds = 0; ds < 4; ++ds) {
        bf16x8 kf = ld8(lds_swc(Ks, 32 + l31, ds * 16 + hi * 8));
        s1 = __builtin_amdgcn_mfma_f32_32x32x16_bf16(kf, qf[ds], s1, 0, 0, 0);
    }
    __builtin_amdgcn_s_setprio(0);

    if (diag) {
#pragma unroll
        for (int r = 0; r < 16; ++r) {
            const int kvr = kv0 + (r & 3) + 8 * (r >> 2) + 4 * hi;
            if (kvr > qrow)      s0[r] = -3.0e38f;
            if (kvr + 32 > qrow) s1[r] = -3.0e38f;
        }
    }
    float mx0 = -3.0e38f, mx1 = -3.0e38f, mx2 = -3.0e38f, mx3 = -3.0e38f;
#pragma unroll
    for (int r = 0; r < 16; r += 4) {
        mx0 = fmaxf(mx0, fmaxf(s0[r],     s1[r]));
        mx1 = fmaxf(mx1, fmaxf(s0[r + 1], s1[r + 1]));
        mx2 = fmaxf(mx2, fmaxf(s0[r + 2], s1[r + 2]));
        mx3 = fmaxf(mx3, fmaxf(s0[r + 3], s1[r + 3]));
    }
    float pmax = fmaxf(fmaxf(mx0, mx1), fmaxf(mx2, mx3));
    pmax = fmaxf(pmax, __shfl_xor(pmax, 32, 64));

    if (__any(pmax > m + 64.0f)) {
        const float mnew = fmaxf(m, pmax);
        const float corr = ex2((m - mnew) * CEXP);
        m = mnew;
        l *= corr;
#pragma unroll
        for (int r = 0; r < 16; ++r) {
            const int cr = (r & 3) + 8 * (r >> 2) + 4 * hi;
            const float c = __shfl(corr, cr, 64);
            o0[r] *= c; o1[r] *= c;
        }
    }

    const float mc = m * CEXP;
    float r0 = 0.f, r1 = 0.f, r2 = 0.f, r3 = 0.f;
    unsigned w0[8], w1[8];
#pragma unroll
    for (int i = 0; i < 8; ++i) {
        const float p0 = ex2(__builtin_fmaf(s0[2 * i],     CEXP, -mc));
        const float p1 = ex2(__builtin_fmaf(s0[2 * i + 1], CEXP, -mc));
        const float p2 = ex2(__builtin_fmaf(s1[2 * i],     CEXP, -mc));
        const float p3 = ex2(__builtin_fmaf(s1[2 * i + 1], CEXP, -mc));
        r0 += p0; r1 += p1; r2 += p2; r3 += p3;
        w0[i] = pack2(p0, p1);
        w1[i] = pack2(p2, p3);
    }
    const float rsum = (r0 + r1) + (r2 + r3);
    l += rsum + __shfl_xor(rsum, 32, 64);

    __builtin_amdgcn_s_setprio(1);
#pragma unroll
    for (int c = 0; c < 2; ++c) {
        const unsigned* w = (c == 0) ? w0 : w1;
        unsigned a0 = w[0], a2 = w[2]; plswap(a0, a2);
        unsigned a1 = w[1], a3 = w[3]; plswap(a1, a3);
        unsigned a4 = w[4], a6 = w[6]; plswap(a4, a6);
        unsigned a5 = w[5], a7 = w[7]; plswap(a5, a7);
        u32x4 lo, hw;
        lo[0] = a0; lo[1] = a1; lo[2] = a2; lo[3] = a3;
        hw[0] = a4; hw[1] = a5; hw[2] = a6; hw[3] = a7;
        const bf16x8 paL = __builtin_bit_cast(bf16x8, lo);
        const bf16x8 paH = __builtin_bit_cast(bf16x8, hw);

        bf16x8 vb;
        vb = ld8(lds_swc(Vts, l31,      c * 32 + hi * 8));
        o0 = __builtin_amdgcn_mfma_f32_32x32x16_bf16(paL, vb, o0, 0, 0, 0);
        vb = ld8(lds_swc(Vts, 32 + l31, c * 32 + hi * 8));
        o1 = __builtin_amdgcn_mfma_f32_32x32x16_bf16(paL, vb, o1, 0, 0, 0);
        vb = ld8(lds_swc(Vts, l31,      c * 32 + 16 + hi * 8));
        o0 = __builtin_amdgcn_mfma_f32_32x32x16_bf16(paH, vb, o0, 0, 0, 0);
        vb = ld8(lds_swc(Vts, 32 + l31, c * 32 + 16 + hi * 8));
        o1 = __builtin_amdgcn_mfma_f32_32x32x16_bf16(paH, vb, o1, 0, 0, 0);
    }
    __builtin_amdgcn_s_setprio(0);
}

// ---------------------------------------------------------------------------
// Causal flash attention (round-9 structure). grid 1024
// (heavy-first: qt = 31 - bid/32), block 128 = 2 warps x 32 q-rows, KV 64.
// Staging via global_load_lds w/ pre-swizzled global source; double-buffered,
// counted vmcnt(8): tile t+1's loads fly during compute(t).
// ---------------------------------------------------------------------------
__global__ __launch_bounds__(128) void attn_kernel(
    const short* __restrict__ Q, const short* __restrict__ K,
    const short* __restrict__ VtG, short* __restrict__ O) {
    __shared__ short KsA[4096], VtsA[4096], KsB[4096], VtsB[4096];

    const int tid = threadIdx.x, lane = tid & 63, wid = tid >> 6;
    const int l31 = lane & 31, hi = lane >> 5;
    const int bid = blockIdx.x;
    const int qt = 31 - (bid >> 5);
    const int bh = bid & 31;
    const int b = bh >> 4, h = bh & 15;
    const size_t base = (size_t)b * 2048 * 1024 + (size_t)h * 64;
    const short* Qp = Q + base;
    const short* Kp = K + base;
    const short* Vp = VtG + (size_t)(h * 64) * 4096 + (size_t)b * 2048;
    short* Op = O + base;

    const int q0w = qt * 64 + wid * 32;
    const int qrow = q0w + l31;

    const int srw = lane >> 3;                 // 0..7
    const int swc = ((lane & 7) ^ srw) * 8;    // swizzled col (elements)
    const short* kSrc = Kp + (size_t)srw * 1024 + swc;
    const short* vSrc = Vp + (size_t)srw * 4096 + swc;
    const int cc0 = wid * 4;

#define ISSUE_TILE(Ksb, Vtsb, kv0_)                                           \
    {                                                                         \
        const int kv0i = (kv0_);                                              \
        _Pragma("unroll")                                                     \
        for (int c = 0; c < 4; ++c) {                                         \
            const int cc = cc0 + c;                                           \
            gload16(kSrc + (size_t)(kv0i + cc * 8) * 1024, (Ksb) + cc * 512); \
            gload16(vSrc + (size_t)(cc * 8) * 4096 + kv0i, (Vtsb) + cc * 512);\
        }                                                                     \
    }

    ISSUE_TILE(KsA, VtsA, 0);

    bf16x8 qf[4];
#pragma unroll
    for (int ds = 0; ds < 4; ++ds)
        qf[ds] = ld8(Qp + (size_t)qrow * 1024 + ds * 16 + hi * 8);

    f32x16 o0 = 0.0f, o1 = 0.0f;
    float m = -INFINITY, l = 0.0f;
    const int ntiles = qt + 1;

#pragma unroll 1
    for (int t = 0; t < ntiles; ++t) {
        const short* Ks  = (t & 1) ? KsB  : KsA;
        const short* Vts = (t & 1) ? VtsB : VtsA;
        if (t + 1 < ntiles) {
            short* Ksn  = (t & 1) ? KsA  : KsB;
            short* Vtsn = (t & 1) ? VtsA : VtsB;
            ISSUE_TILE(Ksn, Vtsn, (t + 1) * 64);
            asm volatile("s_waitcnt vmcnt(8)" ::: "memory");
        } else {
            asm volatile("s_waitcnt vmcnt(0)" ::: "memory");
        }
        __builtin_amdgcn_s_barrier();
        __builtin_amdgcn_sched_barrier(0);
        attn_tile(t * 64, (t * 64 + 63 > q0w), Ks, Vts, qf, o0, o1, m, l, qrow, l31, hi);
        __builtin_amdgcn_s_barrier();
    }
#undef ISSUE_TILE

    const float il = 1.0f / l;
#pragma unroll
    for (int r = 0; r < 16; ++r) {
        const int cr = (r & 3) + 8 * (r >> 2) + 4 * hi;
        const float s = __shfl(il, cr, 64);
        const size_t row = (size_t)(q0w + cr) * 1024;
        Op[row + l31]      = f2bfs(o0[r] * s);
        Op[row + 32 + l31] = f2bfs(o1[r] * s);
    }
}

// ---------------------------------------------------------------------------
extern "C" void kernel_launch(void* const* d_in, const int* in_sizes, int n_in,
                              void* d_out, int out_size, void* d_ws, size_t ws_size,
                              hipStream_t stream) {
    const float* x  = (const float*)d_in[0];
    const float* Wq = (const float*)d_in[1];
    const float* Wk = (const float*)d_in[2];
    const float* Wv = (const float*)d_in[3];
    const float* Wo = (const float*)d_in[4];

    short* wb  = (short*)d_ws;                 // 4 x 1M shorts (8 MB)
    short* Qw  = wb + (size_t)4 * 1048576;     // 8 MB (attn out aliases this)
    short* Kw  = Qw + (size_t)4194304;         // 8 MB
    short* Vtw = Kw + (size_t)4194304;         // 8 MB  (VtG[1024][4096])
    short* xb  = (short*)d_out;                // bf16 x lives in d_out[0:8MB]

    convert_kernel<<<4096, 256, 0, stream>>>(x, Wq, Wk, Wv, Wo, xb, wb);
    gemm_qkv_kernel<<<dim3(32, 24), 256, 0, stream>>>(xb, wb, Qw, Kw, Vtw);
    attn_kernel<<<1024, 128, 0, stream>>>(Qw, Kw, Vtw, Qw);
    gemm_wo_kernel<<<dim3(64, 8), 256, 0, stream>>>(Qw, wb + (size_t)3 * 1048576, (float*)d_out);
}

// Round 14
// 120.343 us; speedup vs baseline: 1.1267x; 1.0220x over previous
//
#include <hip/hip_runtime.h>
#include <hip/hip_bf16.h>

// ---------------------------------------------------------------------------
// MHSA: x[2,2048,1024] f32, Wq/Wk/Wv/Wo[1024,1024] f32 -> out[2,2048,1024] f32.
// Internal bf16. Pipeline (R13 + 1-barrier reg-frag attn loop):
//   1) convert: x -> xb (bf16 in d_out[0:8MB]); W* -> wb (ws)
//   2) fused QKV GEMM: BK=64, XOR-swizzled global_load_lds staging.
//   3) causal flash attention: 2 waves / 64 q-rows, KV-64 dbuf; per tile the
//      16 MFMA fragments are ds_read into REGISTERS right after the (single)
//      barrier; compute runs LDS-free; diagonal tile peeled out of hot loop.
//      P-redistribute via v_permlane32_swap_b32.
//   4) Wo GEMM 64x128 tiles (512 blocks = 2/CU) -> f32 d_out
// ws (shorts): wb[4x1M] Q[4M] K[4M] VtG[4M] = 32 MB. attn out aliases Q.
// ---------------------------------------------------------------------------

#define DEVI __device__ __forceinline__

typedef __bf16 bf16x8 __attribute__((ext_vector_type(8)));
typedef short  short8 __attribute__((ext_vector_type(8)));
typedef float  f32x4  __attribute__((ext_vector_type(4)));
typedef float  f32x16 __attribute__((ext_vector_type(16)));
typedef unsigned int u32x4 __attribute__((ext_vector_type(4)));

DEVI short f2bfs(float f) {
    __hip_bfloat16 h = __float2bfloat16(f);
    return __builtin_bit_cast(short, h);
}
DEVI unsigned pack2(float a, float b) {
    return (unsigned)(unsigned short)f2bfs(a) | ((unsigned)(unsigned short)f2bfs(b) << 16);
}
DEVI bf16x8 ld8(const short* p) {
    return __builtin_bit_cast(bf16x8, *(const short8*)p);
}
DEVI void gload16(const void* g, void* lds) {
    __builtin_amdgcn_global_load_lds(
        (const __attribute__((address_space(1))) void*)g,
        (__attribute__((address_space(3))) void*)lds, 16, 0, 0);
}
// v_permlane32_swap_b32: a.hi <-> b.lo  =>  a' = {a.lo, b.lo}, b' = {a.hi, b.hi}
DEVI void plswap(unsigned& a, unsigned& b) {
    asm volatile("v_permlane32_swap_b32 %0, %1" : "+v"(a), "+v"(b));
}
// XOR-swizzled LDS read address for [64][64] bf16 tiles (involution on the
// 16B slot index within each 128B row): byte ^= (row&7)<<4.
DEVI const short* lds_swc(const short* base, int row, int col) {
    return (const short*)((const char*)base + (((row << 7) + (col << 1)) ^ ((row & 7) << 4)));
}

#if defined(__has_builtin)
#if __has_builtin(__builtin_amdgcn_exp2f)
#define HAVE_EXP2 1
#endif
#endif
DEVI float ex2(float x) {
#ifdef HAVE_EXP2
    return __builtin_amdgcn_exp2f(x);
#else
    return __expf(x * 0.69314718055994531f);
#endif
}
// 0.125 (1/sqrt(64)) folded with log2(e): p = 2^((s - m) * CEXP)
#define CEXP 0.18033688011112042f

// ---------------------------------------------------------------------------
// f32 -> bf16 convert, 1-D exact grid.
// ---------------------------------------------------------------------------
__global__ __launch_bounds__(256) void convert_kernel(
    const float* __restrict__ x, const float* __restrict__ Wq,
    const float* __restrict__ Wk, const float* __restrict__ Wv,
    const float* __restrict__ Wo, short* __restrict__ xb, short* __restrict__ wb) {
    const int bid = blockIdx.x;
    const float* src;
    short* dst;
    int i8;
    if (bid < 2048) {
        src = x; dst = xb;
        i8 = (bid * 256 + threadIdx.x) * 8;
    } else {
        const int w = bid - 2048;
        const int z = w >> 9;                  // 0..3
        src = (z == 0) ? Wq : (z == 1) ? Wk : (z == 2) ? Wv : Wo;
        dst = wb + (size_t)z * 1048576;
        i8 = (((w & 511) * 256) + threadIdx.x) * 8;
    }
    float4 a = ((const float4*)(src + i8))[0];
    float4 b = ((const float4*)(src + i8))[1];
    short8 t;
    t[0] = f2bfs(a.x); t[1] = f2bfs(a.y); t[2] = f2bfs(a.z); t[3] = f2bfs(a.w);
    t[4] = f2bfs(b.x); t[5] = f2bfs(b.y); t[6] = f2bfs(b.z); t[7] = f2bfs(b.w);
    *(short8*)(dst + i8) = t;
}

// ---------------------------------------------------------------------------
// bf16 NT-GEMM K-loop, BK=64, XOR-swizzled staging (conflict-free reads).
// Template: <BM, BN, MF, NF, WN>.  4 waves; wm = wid/WN, wn = wid%WN.
// ---------------------------------------------------------------------------
template <int BM, int BN, int MF, int NF, int WN>
DEVI void gemm_kloop64(const short* __restrict__ A, const short* __restrict__ B,
                       short* As, short* Bs, int wid, int lane, f32x4 acc[MF][NF]) {
    const int l15 = lane & 15, l4 = lane >> 4;
    const int wm = wid / WN, wn = wid % WN;
    const int rowc = lane >> 3;                 // 0..7: row within 8-row chunk
    const int gcol = ((lane & 7) ^ rowc) * 8;   // pre-swizzled 16B slot
    constexpr int NCHA = BM / 8, NCHB = BN / 8;
#pragma unroll 1
    for (int k0 = 0; k0 < 1024; k0 += 64) {
        __syncthreads();
#pragma unroll
        for (int c = wid; c < NCHA; c += 4)
            gload16(A + (size_t)(c * 8 + rowc) * 1024 + k0 + gcol, As + c * 512);
#pragma unroll
        for (int c = wid; c < NCHB; c += 4)
            gload16(B + (size_t)(c * 8 + rowc) * 1024 + k0 + gcol, Bs + c * 512);
        __syncthreads();
#pragma unroll
        for (int kk = 0; kk < 2; ++kk) {
            bf16x8 af[MF], bf[NF];
#pragma unroll
            for (int m = 0; m < MF; ++m) {
                const int row = wm * (MF * 16) + m * 16 + l15;
                af[m] = ld8(As + row * 64 + (((kk * 4 + l4) ^ (row & 7)) * 8));
            }
#pragma unroll
            for (int n = 0; n < NF; ++n) {
                const int row = wn * (NF * 16) + n * 16 + l15;
                bf[n] = ld8(Bs + row * 64 + (((kk * 4 + l4) ^ (row & 7)) * 8));
            }
#pragma unroll
            for (int m = 0; m < MF; ++m)
#pragma unroll
                for (int n = 0; n < NF; ++n)
                    acc[m][n] = __builtin_amdgcn_mfma_f32_16x16x32_bf16(af[m], bf[n], acc[m][n], 0, 0, 0);
        }
    }
}

// ---------------------------------------------------------------------------
// Fused QKV projection. grid (32, 24): y>>3 selects weight; (y&7) col tile.
// ---------------------------------------------------------------------------
__global__ __launch_bounds__(256) void gemm_qkv_kernel(
    const short* __restrict__ xb, const short* __restrict__ wb,
    short* __restrict__ Qo, short* __restrict__ Ko, short* __restrict__ VtG) {
    __shared__ short As[8192], Bs[8192];
    const int tid = threadIdx.x, lane = tid & 63, wid = tid >> 6;
    const int l15 = lane & 15, l4 = lane >> 4;
    const int wm = wid >> 1, wn = wid & 1;
    const int y = blockIdx.y, wsel = y >> 3;
    const int row0 = blockIdx.x * 128, col0 = (y & 7) * 128;

    f32x4 acc[4][4] = {};
    gemm_kloop64<128, 128, 4, 4, 2>(
        xb + (size_t)row0 * 1024,
        wb + (size_t)wsel * 1048576 + (size_t)col0 * 1024,
        As, Bs, wid, lane, acc);

    if (wsel == 2) {
#pragma unroll
        for (int m = 0; m < 4; ++m)
#pragma unroll
            for (int n = 0; n < 4; ++n)
#pragma unroll
                for (int j = 0; j < 4; ++j) {
                    int row = row0 + wm * 64 + m * 16 + l4 * 4 + j;
                    int col = col0 + wn * 64 + n * 16 + l15;
                    VtG[(size_t)col * 4096 + row] = f2bfs(acc[m][n][j]);
                }
    } else {
        short* C = (wsel == 0) ? Qo : Ko;
#pragma unroll
        for (int m = 0; m < 4; ++m)
#pragma unroll
            for (int n = 0; n < 4; ++n)
#pragma unroll
                for (int j = 0; j < 4; ++j) {
                    int row = row0 + wm * 64 + m * 16 + l4 * 4 + j;
                    int col = col0 + wn * 64 + n * 16 + l15;
                    C[(size_t)row * 1024 + col] = f2bfs(acc[m][n][j]);
                }
    }
}

// ---------------------------------------------------------------------------
// Output projection: 64x128 tile (512 blocks = 2/CU), BK=64. Waves 1x4.
// ---------------------------------------------------------------------------
__global__ __launch_bounds__(256) void gemm_wo_kernel(
    const short* __restrict__ Ao, const short* __restrict__ Wob,
    float* __restrict__ Cout) {
    __shared__ short As[4096], Bs[8192];
    const int tid = threadIdx.x, lane = tid & 63, wid = tid >> 6;
    const int l15 = lane & 15, l4 = lane >> 4;
    const int wn = wid;                       // WN=4: wm = 0
    const int row0 = blockIdx.x * 64, col0 = blockIdx.y * 128;

    f32x4 acc[4][2] = {};
    gemm_kloop64<64, 128, 4, 2, 4>(
        Ao + (size_t)row0 * 1024, Wob + (size_t)col0 * 1024,
        As, Bs, wid, lane, acc);

#pragma unroll
    for (int m = 0; m < 4; ++m)
#pragma unroll
        for (int n = 0; n < 2; ++n)
#pragma unroll
            for (int j = 0; j < 4; ++j) {
                int row = row0 + m * 16 + l4 * 4 + j;
                int col = col0 + wn * 32 + n * 16 + l15;
                Cout[(size_t)row * 1024 + col] = acc[m][n][j];
            }
}

// ---------------------------------------------------------------------------
// Read the 16 MFMA fragments of one KV tile from (swizzled) LDS into regs.
// ---------------------------------------------------------------------------
DEVI void read_frags(const short* Ks, const short* Vts, int l31, int hi,
                     bf16x8 kf[8], bf16x8 vb[8]) {
#pragma unroll
    for (int ds = 0; ds < 4; ++ds) {
        kf[ds]     = ld8(lds_swc(Ks, l31,      ds * 16 + hi * 8));
        kf[4 + ds] = ld8(lds_swc(Ks, 32 + l31, ds * 16 + hi * 8));
    }
#pragma unroll
    for (int c = 0; c < 2; ++c) {
        vb[c * 4 + 0] = ld8(lds_swc(Vts, l31,      c * 32 + hi * 8));
        vb[c * 4 + 1] = ld8(lds_swc(Vts, 32 + l31, c * 32 + hi * 8));
        vb[c * 4 + 2] = ld8(lds_swc(Vts, l31,      c * 32 + 16 + hi * 8));
        vb[c * 4 + 3] = ld8(lds_swc(Vts, 32 + l31, c * 32 + 16 + hi * 8));
    }
}

// ---------------------------------------------------------------------------
// One KV tile, operands in registers: S = K Q^T, exp2-domain online softmax,
// defer-max, permlane32_swap P-redistribute, O += P V.  (verified math)
// ---------------------------------------------------------------------------
template <bool DIAG>
DEVI void attn_tile_r(int kv0, const bf16x8 kf[8], const bf16x8 vb[8],
                      const bf16x8 qf[4], f32x16& o0, f32x16& o1,
                      float& m, float& l, int qrow, int hi) {
    f32x16 s0 = 0.0f, s1 = 0.0f;
    __builtin_amdgcn_s_setprio(1);
#pragma unroll
    for (int ds = 0; ds < 4; ++ds)
        s0 = __builtin_amdgcn_mfma_f32_32x32x16_bf16(kf[ds], qf[ds], s0, 0, 0, 0);
#pragma unroll
    for (int ds = 0; ds < 4; ++ds)
        s1 = __builtin_amdgcn_mfma_f32_32x32x16_bf16(kf[4 + ds], qf[ds], s1, 0, 0, 0);
    __builtin_amdgcn_s_setprio(0);

    if (DIAG) {
#pragma unroll
        for (int r = 0; r < 16; ++r) {
            const int kvr = kv0 + (r & 3) + 8 * (r >> 2) + 4 * hi;
            if (kvr > qrow)      s0[r] = -3.0e38f;
            if (kvr + 32 > qrow) s1[r] = -3.0e38f;
        }
    }
    float mx0 = -3.0e38f, mx1 = -3.0e38f, mx2 = -3.0e38f, mx3 = -3.0e38f;
#pragma unroll
    for (int r = 0; r < 16; r += 4) {
        mx0 = fmaxf(mx0, fmaxf(s0[r],     s1[r]));
        mx1 = fmaxf(mx1, fmaxf(s0[r + 1], s1[r + 1]));
        mx2 = fmaxf(mx2, fmaxf(s0[r + 2], s1[r + 2]));
        mx3 = fmaxf(mx3, fmaxf(s0[r + 3], s1[r + 3]));
    }
    float pmax = fmaxf(fmaxf(mx0, mx1), fmaxf(mx2, mx3));
    pmax = fmaxf(pmax, __shfl_xor(pmax, 32, 64));

    if (__any(pmax > m + 64.0f)) {
        const float mnew = fmaxf(m, pmax);
        const float corr = ex2((m - mnew) * CEXP);
        m = mnew;
        l *= corr;
#pragma unroll
        for (int r = 0; r < 16; ++r) {
            const int cr = (r & 3) + 8 * (r >> 2) + 4 * hi;
            const float c = __shfl(corr, cr, 64);
            o0[r] *= c; o1[r] *= c;
        }
    }

    const float mc = m * CEXP;
    float r0 = 0.f, r1 = 0.f, r2 = 0.f, r3 = 0.f;
    unsigned w0[8], w1[8];
#pragma unroll
    for (int i = 0; i < 8; ++i) {
        const float p0 = ex2(__builtin_fmaf(s0[2 * i],     CEXP, -mc));
        const float p1 = ex2(__builtin_fmaf(s0[2 * i + 1], CEXP, -mc));
        const float p2 = ex2(__builtin_fmaf(s1[2 * i],     CEXP, -mc));
        const float p3 = ex2(__builtin_fmaf(s1[2 * i + 1], CEXP, -mc));
        r0 += p0; r1 += p1; r2 += p2; r3 += p3;
        w0[i] = pack2(p0, p1);
        w1[i] = pack2(p2, p3);
    }
    const float rsum = (r0 + r1) + (r2 + r3);
    l += rsum + __shfl_xor(rsum, 32, 64);

    __builtin_amdgcn_s_setprio(1);
#pragma unroll
    for (int c = 0; c < 2; ++c) {
        const unsigned* w = (c == 0) ? w0 : w1;
        unsigned a0 = w[0], a2 = w[2]; plswap(a0, a2);
        unsigned a1 = w[1], a3 = w[3]; plswap(a1, a3);
        unsigned a4 = w[4], a6 = w[6]; plswap(a4, a6);
        unsigned a5 = w[5], a7 = w[7]; plswap(a5, a7);
        u32x4 lo, hw;
        lo[0] = a0; lo[1] = a1; lo[2] = a2; lo[3] = a3;
        hw[0] = a4; hw[1] = a5; hw[2] = a6; hw[3] = a7;
        const bf16x8 paL = __builtin_bit_cast(bf16x8, lo);
        const bf16x8 paH = __builtin_bit_cast(bf16x8, hw);

        o0 = __builtin_amdgcn_mfma_f32_32x32x16_bf16(paL, vb[c * 4 + 0], o0, 0, 0, 0);
        o1 = __builtin_amdgcn_mfma_f32_32x32x16_bf16(paL, vb[c * 4 + 1], o1, 0, 0, 0);
        o0 = __builtin_amdgcn_mfma_f32_32x32x16_bf16(paH, vb[c * 4 + 2], o0, 0, 0, 0);
        o1 = __builtin_amdgcn_mfma_f32_32x32x16_bf16(paH, vb[c * 4 + 3], o1, 0, 0, 0);
    }
    __builtin_amdgcn_s_setprio(0);
}

// ---------------------------------------------------------------------------
// Causal flash attention, 1-barrier reg-frag pipeline. grid 1024
// (heavy-first: qt = 31 - bid/32), block 128 = 2 warps x 32 q-rows, KV 64.
// Per tile: compute(t) runs from registers; then lgkmcnt(0)+vmcnt(0)+barrier
// (lgkmcnt makes buf[t&1] WAR-safe for both waves), ds_read frags(t+1) to
// regs, ISSUE(t+2) into buf[t&1]. Diagonal tile peeled (mask-free hot loop).
// ---------------------------------------------------------------------------
__global__ __launch_bounds__(128) void attn_kernel(
    const short* __restrict__ Q, const short* __restrict__ K,
    const short* __restrict__ VtG, short* __restrict__ O) {
    __shared__ short KsA[4096], VtsA[4096], KsB[4096], VtsB[4096];

    const int tid = threadIdx.x, lane = tid & 63, wid = tid >> 6;
    const int l31 = lane & 31, hi = lane >> 5;
    const int bid = blockIdx.x;
    const int qt = 31 - (bid >> 5);
    const int bh = bid & 31;
    const int b = bh >> 4, h = bh & 15;
    const size_t base = (size_t)b * 2048 * 1024 + (size_t)h * 64;
    const short* Qp = Q + base;
    const short* Kp = K + base;
    const short* Vp = VtG + (size_t)(h * 64) * 4096 + (size_t)b * 2048;
    short* Op = O + base;

    const int q0w = qt * 64 + wid * 32;
    const int qrow = q0w + l31;

    const int srw = lane >> 3;                 // 0..7
    const int swc = ((lane & 7) ^ srw) * 8;    // swizzled col (elements)
    const short* kSrc = Kp + (size_t)srw * 1024 + swc;
    const short* vSrc = Vp + (size_t)srw * 4096 + swc;
    const int cc0 = wid * 4;

#define ISSUE_TILE(Ksb, Vtsb, kv0_)                                           \
    {                                                                         \
        const int kv0i = (kv0_);                                              \
        _Pragma("unroll")                                                     \
        for (int c = 0; c < 4; ++c) {                                         \
            const int cc = cc0 + c;                                           \
            gload16(kSrc + (size_t)(kv0i + cc * 8) * 1024, (Ksb) + cc * 512); \
            gload16(vSrc + (size_t)(cc * 8) * 4096 + kv0i, (Vtsb) + cc * 512);\
        }                                                                     \
    }

    const int nt = qt + 1;

    // ---- prologue: stage tile 0, read its frags, start tile 1 ----
    ISSUE_TILE(KsA, VtsA, 0);

    bf16x8 qf[4];
#pragma unroll
    for (int ds = 0; ds < 4; ++ds)
        qf[ds] = ld8(Qp + (size_t)qrow * 1024 + ds * 16 + hi * 8);

    asm volatile("s_waitcnt vmcnt(0)" ::: "memory");
    __builtin_amdgcn_s_barrier();
    __builtin_amdgcn_sched_barrier(0);

    bf16x8 kf[8], vb[8];
    read_frags(KsA, VtsA, l31, hi, kf, vb);
    __builtin_amdgcn_sched_barrier(0);
    if (nt > 1) ISSUE_TILE(KsB, VtsB, 64);

    f32x16 o0 = 0.0f, o1 = 0.0f;
    float m = -INFINITY, l = 0.0f;

    // ---- hot loop: tiles 0..nt-2 (mask-free) ----
#pragma unroll 1
    for (int t = 0; t < nt - 1; ++t) {
        attn_tile_r<false>(t * 64, kf, vb, qf, o0, o1, m, l, qrow, hi);
        asm volatile("s_waitcnt lgkmcnt(0) vmcnt(0)" ::: "memory");
        __builtin_amdgcn_s_barrier();
        __builtin_amdgcn_sched_barrier(0);
        const short* Ksn  = (t & 1) ? KsA  : KsB;   // buf[(t+1)&1]
        const short* Vtsn = (t & 1) ? VtsA : VtsB;
        read_frags(Ksn, Vtsn, l31, hi, kf, vb);
        __builtin_amdgcn_sched_barrier(0);
        if (t + 2 < nt) {
            short* Kso  = (t & 1) ? KsB  : KsA;     // buf[t&1] (consumed)
            short* Vtso = (t & 1) ? VtsB : VtsA;
            ISSUE_TILE(Kso, Vtso, (t + 2) * 64);
        }
    }

    // ---- peeled diagonal tile ----
    attn_tile_r<true>((nt - 1) * 64, kf, vb, qf, o0, o1, m, l, qrow, hi);
#undef ISSUE_TILE

    const float il = 1.0f / l;
#pragma unroll
    for (int r = 0; r < 16; ++r) {
        const int cr = (r & 3) + 8 * (r >> 2) + 4 * hi;
        const float s = __shfl(il, cr, 64);
        const size_t row = (size_t)(q0w + cr) * 1024;
        Op[row + l31]      = f2bfs(o0[r] * s);
        Op[row + 32 + l31] = f2bfs(o1[r] * s);
    }
}

// ---------------------------------------------------------------------------
extern "C" void kernel_launch(void* const* d_in, const int* in_sizes, int n_in,
                              void* d_out, int out_size, void* d_ws, size_t ws_size,
                              hipStream_t stream) {
    const float* x  = (const float*)d_in[0];
    const float* Wq = (const float*)d_in[1];
    const float* Wk = (const float*)d_in[2];
    const float* Wv = (const float*)d_in[3];
    const float* Wo = (const float*)d_in[4];

    short* wb  = (short*)d_ws;                 // 4 x 1M shorts (8 MB)
    short* Qw  = wb + (size_t)4 * 1048576;     // 8 MB (attn out aliases this)
    short* Kw  = Qw + (size_t)4194304;         // 8 MB
    short* Vtw = Kw + (size_t)4194304;         // 8 MB  (VtG[1024][4096])
    short* xb  = (short*)d_out;                // bf16 x lives in d_out[0:8MB]

    convert_kernel<<<4096, 256, 0, stream>>>(x, Wq, Wk, Wv, Wo, xb, wb);
    gemm_qkv_kernel<<<dim3(32, 24), 256, 0, stream>>>(xb, wb, Qw, Kw, Vtw);
    attn_kernel<<<1024, 128, 0, stream>>>(Qw, Kw, Vtw, Qw);
    gemm_wo_kernel<<<dim3(64, 8), 256, 0, stream>>>(Qw, wb + (size_t)3 * 1048576, (float*)d_out);
}

// Round 15
// 115.755 us; speedup vs baseline: 1.1713x; 1.0396x over previous
//
#include <hip/hip_runtime.h>
#include <hip/hip_bf16.h>

// ---------------------------------------------------------------------------
// MHSA: x[2,2048,1024] f32, Wq/Wk/Wv/Wo[1024,1024] f32 -> out[2,2048,1024] f32.
// Internal bf16. Pipeline (R14 + cheap P-pack + deferred l-sum + issue-first):
//   1) convert: x -> xb (bf16 in d_out[0:8MB]); W* -> wb (ws)
//   2) fused QKV GEMM: BK=64, XOR-swizzled global_load_lds staging.
//   3) causal flash attention: 2 waves / 64 q-rows, KV-64 dbuf, 1 barrier/tile,
//      reg-held MFMA frags; P->bf16 via bias+v_perm_b32 (3 ops/pair vs ~10);
//      l cross-lane sum deferred to epilogue; ISSUE(t+2) precedes frag reads.
//   4) Wo GEMM 64x128 tiles (512 blocks = 2/CU) -> f32 d_out
// ws (shorts): wb[4x1M] Q[4M] K[4M] VtG[4M] = 32 MB. attn out aliases Q.
// ---------------------------------------------------------------------------

#define DEVI __device__ __forceinline__

typedef __bf16 bf16x8 __attribute__((ext_vector_type(8)));
typedef short  short8 __attribute__((ext_vector_type(8)));
typedef float  f32x4  __attribute__((ext_vector_type(4)));
typedef float  f32x16 __attribute__((ext_vector_type(16)));
typedef unsigned int u32x4 __attribute__((ext_vector_type(4)));

DEVI short f2bfs(float f) {
    __hip_bfloat16 h = __float2bfloat16(f);
    return __builtin_bit_cast(short, h);
}
// cheap bf16 pair pack: +0.5ulp bias then byte-perm the two hi-halves.
// dst low16 = bf16(a), high16 = bf16(b).  (ties-away rounding; P>=0 safe)
DEVI unsigned pack2rb(float a, float b) {
    const unsigned ua = __builtin_bit_cast(unsigned, a) + 0x8000u;
    const unsigned ub = __builtin_bit_cast(unsigned, b) + 0x8000u;
    return __builtin_amdgcn_perm(ub, ua, 0x07060302u);
}
DEVI bf16x8 ld8(const short* p) {
    return __builtin_bit_cast(bf16x8, *(const short8*)p);
}
DEVI void gload16(const void* g, void* lds) {
    __builtin_amdgcn_global_load_lds(
        (const __attribute__((address_space(1))) void*)g,
        (__attribute__((address_space(3))) void*)lds, 16, 0, 0);
}
// v_permlane32_swap_b32: a.hi <-> b.lo  =>  a' = {a.lo, b.lo}, b' = {a.hi, b.hi}
DEVI void plswap(unsigned& a, unsigned& b) {
    asm volatile("v_permlane32_swap_b32 %0, %1" : "+v"(a), "+v"(b));
}
// XOR-swizzled LDS read address for [64][64] bf16 tiles (involution on the
// 16B slot index within each 128B row): byte ^= (row&7)<<4.
DEVI const short* lds_swc(const short* base, int row, int col) {
    return (const short*)((const char*)base + (((row << 7) + (col << 1)) ^ ((row & 7) << 4)));
}

#if defined(__has_builtin)
#if __has_builtin(__builtin_amdgcn_exp2f)
#define HAVE_EXP2 1
#endif
#endif
DEVI float ex2(float x) {
#ifdef HAVE_EXP2
    return __builtin_amdgcn_exp2f(x);
#else
    return __expf(x * 0.69314718055994531f);
#endif
}
// 0.125 (1/sqrt(64)) folded with log2(e): p = 2^((s - m) * CEXP)
#define CEXP 0.18033688011112042f

// ---------------------------------------------------------------------------
// f32 -> bf16 convert, 1-D exact grid.
// ---------------------------------------------------------------------------
__global__ __launch_bounds__(256) void convert_kernel(
    const float* __restrict__ x, const float* __restrict__ Wq,
    const float* __restrict__ Wk, const float* __restrict__ Wv,
    const float* __restrict__ Wo, short* __restrict__ xb, short* __restrict__ wb) {
    const int bid = blockIdx.x;
    const float* src;
    short* dst;
    int i8;
    if (bid < 2048) {
        src = x; dst = xb;
        i8 = (bid * 256 + threadIdx.x) * 8;
    } else {
        const int w = bid - 2048;
        const int z = w >> 9;                  // 0..3
        src = (z == 0) ? Wq : (z == 1) ? Wk : (z == 2) ? Wv : Wo;
        dst = wb + (size_t)z * 1048576;
        i8 = (((w & 511) * 256) + threadIdx.x) * 8;
    }
    float4 a = ((const float4*)(src + i8))[0];
    float4 b = ((const float4*)(src + i8))[1];
    short8 t;
    t[0] = f2bfs(a.x); t[1] = f2bfs(a.y); t[2] = f2bfs(a.z); t[3] = f2bfs(a.w);
    t[4] = f2bfs(b.x); t[5] = f2bfs(b.y); t[6] = f2bfs(b.z); t[7] = f2bfs(b.w);
    *(short8*)(dst + i8) = t;
}

// ---------------------------------------------------------------------------
// bf16 NT-GEMM K-loop, BK=64, XOR-swizzled staging (conflict-free reads).
// Template: <BM, BN, MF, NF, WN>.  4 waves; wm = wid/WN, wn = wid%WN.
// ---------------------------------------------------------------------------
template <int BM, int BN, int MF, int NF, int WN>
DEVI void gemm_kloop64(const short* __restrict__ A, const short* __restrict__ B,
                       short* As, short* Bs, int wid, int lane, f32x4 acc[MF][NF]) {
    const int l15 = lane & 15, l4 = lane >> 4;
    const int wm = wid / WN, wn = wid % WN;
    const int rowc = lane >> 3;                 // 0..7: row within 8-row chunk
    const int gcol = ((lane & 7) ^ rowc) * 8;   // pre-swizzled 16B slot
    constexpr int NCHA = BM / 8, NCHB = BN / 8;
#pragma unroll 1
    for (int k0 = 0; k0 < 1024; k0 += 64) {
        __syncthreads();
#pragma unroll
        for (int c = wid; c < NCHA; c += 4)
            gload16(A + (size_t)(c * 8 + rowc) * 1024 + k0 + gcol, As + c * 512);
#pragma unroll
        for (int c = wid; c < NCHB; c += 4)
            gload16(B + (size_t)(c * 8 + rowc) * 1024 + k0 + gcol, Bs + c * 512);
        __syncthreads();
#pragma unroll
        for (int kk = 0; kk < 2; ++kk) {
            bf16x8 af[MF], bf[NF];
#pragma unroll
            for (int m = 0; m < MF; ++m) {
                const int row = wm * (MF * 16) + m * 16 + l15;
                af[m] = ld8(As + row * 64 + (((kk * 4 + l4) ^ (row & 7)) * 8));
            }
#pragma unroll
            for (int n = 0; n < NF; ++n) {
                const int row = wn * (NF * 16) + n * 16 + l15;
                bf[n] = ld8(Bs + row * 64 + (((kk * 4 + l4) ^ (row & 7)) * 8));
            }
#pragma unroll
            for (int m = 0; m < MF; ++m)
#pragma unroll
                for (int n = 0; n < NF; ++n)
                    acc[m][n] = __builtin_amdgcn_mfma_f32_16x16x32_bf16(af[m], bf[n], acc[m][n], 0, 0, 0);
        }
    }
}

// ---------------------------------------------------------------------------
// Fused QKV projection. grid (32, 24): y>>3 selects weight; (y&7) col tile.
// ---------------------------------------------------------------------------
__global__ __launch_bounds__(256) void gemm_qkv_kernel(
    const short* __restrict__ xb, const short* __restrict__ wb,
    short* __restrict__ Qo, short* __restrict__ Ko, short* __restrict__ VtG) {
    __shared__ short As[8192], Bs[8192];
    const int tid = threadIdx.x, lane = tid & 63, wid = tid >> 6;
    const int l15 = lane & 15, l4 = lane >> 4;
    const int wm = wid >> 1, wn = wid & 1;
    const int y = blockIdx.y, wsel = y >> 3;
    const int row0 = blockIdx.x * 128, col0 = (y & 7) * 128;

    f32x4 acc[4][4] = {};
    gemm_kloop64<128, 128, 4, 4, 2>(
        xb + (size_t)row0 * 1024,
        wb + (size_t)wsel * 1048576 + (size_t)col0 * 1024,
        As, Bs, wid, lane, acc);

    if (wsel == 2) {
#pragma unroll
        for (int m = 0; m < 4; ++m)
#pragma unroll
            for (int n = 0; n < 4; ++n)
#pragma unroll
                for (int j = 0; j < 4; ++j) {
                    int row = row0 + wm * 64 + m * 16 + l4 * 4 + j;
                    int col = col0 + wn * 64 + n * 16 + l15;
                    VtG[(size_t)col * 4096 + row] = f2bfs(acc[m][n][j]);
                }
    } else {
        short* C = (wsel == 0) ? Qo : Ko;
#pragma unroll
        for (int m = 0; m < 4; ++m)
#pragma unroll
            for (int n = 0; n < 4; ++n)
#pragma unroll
                for (int j = 0; j < 4; ++j) {
                    int row = row0 + wm * 64 + m * 16 + l4 * 4 + j;
                    int col = col0 + wn * 64 + n * 16 + l15;
                    C[(size_t)row * 1024 + col] = f2bfs(acc[m][n][j]);
                }
    }
}

// ---------------------------------------------------------------------------
// Output projection: 64x128 tile (512 blocks = 2/CU), BK=64. Waves 1x4.
// ---------------------------------------------------------------------------
__global__ __launch_bounds__(256) void gemm_wo_kernel(
    const short* __restrict__ Ao, const short* __restrict__ Wob,
    float* __restrict__ Cout) {
    __shared__ short As[4096], Bs[8192];
    const int tid = threadIdx.x, lane = tid & 63, wid = tid >> 6;
    const int l15 = lane & 15, l4 = lane >> 4;
    const int wn = wid;                       // WN=4: wm = 0
    const int row0 = blockIdx.x * 64, col0 = blockIdx.y * 128;

    f32x4 acc[4][2] = {};
    gemm_kloop64<64, 128, 4, 2, 4>(
        Ao + (size_t)row0 * 1024, Wob + (size_t)col0 * 1024,
        As, Bs, wid, lane, acc);

#pragma unroll
    for (int m = 0; m < 4; ++m)
#pragma unroll
        for (int n = 0; n < 2; ++n)
#pragma unroll
            for (int j = 0; j < 4; ++j) {
                int row = row0 + m * 16 + l4 * 4 + j;
                int col = col0 + wn * 32 + n * 16 + l15;
                Cout[(size_t)row * 1024 + col] = acc[m][n][j];
            }
}

// ---------------------------------------------------------------------------
// Read the 16 MFMA fragments of one KV tile from (swizzled) LDS into regs.
// ---------------------------------------------------------------------------
DEVI void read_frags(const short* Ks, const short* Vts, int l31, int hi,
                     bf16x8 kf[8], bf16x8 vb[8]) {
#pragma unroll
    for (int ds = 0; ds < 4; ++ds) {
        kf[ds]     = ld8(lds_swc(Ks, l31,      ds * 16 + hi * 8));
        kf[4 + ds] = ld8(lds_swc(Ks, 32 + l31, ds * 16 + hi * 8));
    }
#pragma unroll
    for (int c = 0; c < 2; ++c) {
        vb[c * 4 + 0] = ld8(lds_swc(Vts, l31,      c * 32 + hi * 8));
        vb[c * 4 + 1] = ld8(lds_swc(Vts, 32 + l31, c * 32 + hi * 8));
        vb[c * 4 + 2] = ld8(lds_swc(Vts, l31,      c * 32 + 16 + hi * 8));
        vb[c * 4 + 3] = ld8(lds_swc(Vts, 32 + l31, c * 32 + 16 + hi * 8));
    }
}

// ---------------------------------------------------------------------------
// One KV tile, operands in registers: S = K Q^T, exp2-domain online softmax,
// defer-max, perm-packed P, permlane32_swap redistribute, O += P V.
// l is accumulated per-lane; the cross-lane (hi-pair) sum is deferred to the
// epilogue (corr is pair-uniform because pmax is shfl-merged before use).
// ---------------------------------------------------------------------------
template <bool DIAG>
DEVI void attn_tile_r(int kv0, const bf16x8 kf[8], const bf16x8 vb[8],
                      const bf16x8 qf[4], f32x16& o0, f32x16& o1,
                      float& m, float& l, int qrow, int hi) {
    f32x16 s0 = 0.0f, s1 = 0.0f;
    __builtin_amdgcn_s_setprio(1);
#pragma unroll
    for (int ds = 0; ds < 4; ++ds)
        s0 = __builtin_amdgcn_mfma_f32_32x32x16_bf16(kf[ds], qf[ds], s0, 0, 0, 0);
#pragma unroll
    for (int ds = 0; ds < 4; ++ds)
        s1 = __builtin_amdgcn_mfma_f32_32x32x16_bf16(kf[4 + ds], qf[ds], s1, 0, 0, 0);
    __builtin_amdgcn_s_setprio(0);

    if (DIAG) {
#pragma unroll
        for (int r = 0; r < 16; ++r) {
            const int kvr = kv0 + (r & 3) + 8 * (r >> 2) + 4 * hi;
            if (kvr > qrow)      s0[r] = -3.0e38f;
            if (kvr + 32 > qrow) s1[r] = -3.0e38f;
        }
    }
    float mx0 = -3.0e38f, mx1 = -3.0e38f, mx2 = -3.0e38f, mx3 = -3.0e38f;
#pragma unroll
    for (int r = 0; r < 16; r += 4) {
        mx0 = fmaxf(mx0, fmaxf(s0[r],     s1[r]));
        mx1 = fmaxf(mx1, fmaxf(s0[r + 1], s1[r + 1]));
        mx2 = fmaxf(mx2, fmaxf(s0[r + 2], s1[r + 2]));
        mx3 = fmaxf(mx3, fmaxf(s0[r + 3], s1[r + 3]));
    }
    float pmax = fmaxf(fmaxf(mx0, mx1), fmaxf(mx2, mx3));
    pmax = fmaxf(pmax, __shfl_xor(pmax, 32, 64));

    if (__any(pmax > m + 64.0f)) {
        const float mnew = fmaxf(m, pmax);
        const float corr = ex2((m - mnew) * CEXP);
        m = mnew;
        l *= corr;
#pragma unroll
        for (int r = 0; r < 16; ++r) {
            const int cr = (r & 3) + 8 * (r >> 2) + 4 * hi;
            const float c = __shfl(corr, cr, 64);
            o0[r] *= c; o1[r] *= c;
        }
    }

    const float mc = m * CEXP;
    float r0 = 0.f, r1 = 0.f, r2 = 0.f, r3 = 0.f;
    unsigned w0[8], w1[8];
#pragma unroll
    for (int i = 0; i < 8; ++i) {
        const float p0 = ex2(__builtin_fmaf(s0[2 * i],     CEXP, -mc));
        const float p1 = ex2(__builtin_fmaf(s0[2 * i + 1], CEXP, -mc));
        const float p2 = ex2(__builtin_fmaf(s1[2 * i],     CEXP, -mc));
        const float p3 = ex2(__builtin_fmaf(s1[2 * i + 1], CEXP, -mc));
        r0 += p0; r1 += p1; r2 += p2; r3 += p3;
        w0[i] = pack2rb(p0, p1);
        w1[i] = pack2rb(p2, p3);
    }
    l += (r0 + r1) + (r2 + r3);      // cross-lane sum deferred to epilogue

    __builtin_amdgcn_s_setprio(1);
#pragma unroll
    for (int c = 0; c < 2; ++c) {
        const unsigned* w = (c == 0) ? w0 : w1;
        unsigned a0 = w[0], a2 = w[2]; plswap(a0, a2);
        unsigned a1 = w[1], a3 = w[3]; plswap(a1, a3);
        unsigned a4 = w[4], a6 = w[6]; plswap(a4, a6);
        unsigned a5 = w[5], a7 = w[7]; plswap(a5, a7);
        u32x4 lo, hw;
        lo[0] = a0; lo[1] = a1; lo[2] = a2; lo[3] = a3;
        hw[0] = a4; hw[1] = a5; hw[2] = a6; hw[3] = a7;
        const bf16x8 paL = __builtin_bit_cast(bf16x8, lo);
        const bf16x8 paH = __builtin_bit_cast(bf16x8, hw);

        o0 = __builtin_amdgcn_mfma_f32_32x32x16_bf16(paL, vb[c * 4 + 0], o0, 0, 0, 0);
        o1 = __builtin_amdgcn_mfma_f32_32x32x16_bf16(paL, vb[c * 4 + 1], o1, 0, 0, 0);
        o0 = __builtin_amdgcn_mfma_f32_32x32x16_bf16(paH, vb[c * 4 + 2], o0, 0, 0, 0);
        o1 = __builtin_amdgcn_mfma_f32_32x32x16_bf16(paH, vb[c * 4 + 3], o1, 0, 0, 0);
    }
    __builtin_amdgcn_s_setprio(0);
}

// ---------------------------------------------------------------------------
// Causal flash attention, 1-barrier reg-frag pipeline. grid 1024
// (heavy-first: qt = 31 - bid/32), block 128 = 2 warps x 32 q-rows, KV 64.
// Per tile: compute(t) from registers; lgkmcnt(0)+vmcnt(0)+barrier; ISSUE(t+2)
// into buf[t&1] (WAR-safe: all reads of it drained before the barrier);
// ds_read frags(t+1). Diagonal tile peeled (mask-free hot loop).
// ---------------------------------------------------------------------------
__global__ __launch_bounds__(128) void attn_kernel(
    const short* __restrict__ Q, const short* __restrict__ K,
    const short* __restrict__ VtG, short* __restrict__ O) {
    __shared__ short KsA[4096], VtsA[4096], KsB[4096], VtsB[4096];

    const int tid = threadIdx.x, lane = tid & 63, wid = tid >> 6;
    const int l31 = lane & 31, hi = lane >> 5;
    const int bid = blockIdx.x;
    const int qt = 31 - (bid >> 5);
    const int bh = bid & 31;
    const int b = bh >> 4, h = bh & 15;
    const size_t base = (size_t)b * 2048 * 1024 + (size_t)h * 64;
    const short* Qp = Q + base;
    const short* Kp = K + base;
    const short* Vp = VtG + (size_t)(h * 64) * 4096 + (size_t)b * 2048;
    short* Op = O + base;

    const int q0w = qt * 64 + wid * 32;
    const int qrow = q0w + l31;

    const int srw = lane >> 3;                 // 0..7
    const int swc = ((lane & 7) ^ srw) * 8;    // swizzled col (elements)
    const short* kSrc = Kp + (size_t)srw * 1024 + swc;
    const short* vSrc = Vp + (size_t)srw * 4096 + swc;
    const int cc0 = wid * 4;

#define ISSUE_TILE(Ksb, Vtsb, kv0_)                                           \
    {                                                                         \
        const int kv0i = (kv0_);                                              \
        _Pragma("unroll")                                                     \
        for (int c = 0; c < 4; ++c) {                                         \
            const int cc = cc0 + c;                                           \
            gload16(kSrc + (size_t)(kv0i + cc * 8) * 1024, (Ksb) + cc * 512); \
            gload16(vSrc + (size_t)(cc * 8) * 4096 + kv0i, (Vtsb) + cc * 512);\
        }                                                                     \
    }

    const int nt = qt + 1;

    // ---- prologue: stage tile 0, start tile 1, read tile-0 frags ----
    ISSUE_TILE(KsA, VtsA, 0);

    bf16x8 qf[4];
#pragma unroll
    for (int ds = 0; ds < 4; ++ds)
        qf[ds] = ld8(Qp + (size_t)qrow * 1024 + ds * 16 + hi * 8);

    asm volatile("s_waitcnt vmcnt(0)" ::: "memory");
    __builtin_amdgcn_s_barrier();
    __builtin_amdgcn_sched_barrier(0);

    if (nt > 1) ISSUE_TILE(KsB, VtsB, 64);
    bf16x8 kf[8], vb[8];
    read_frags(KsA, VtsA, l31, hi, kf, vb);
    __builtin_amdgcn_sched_barrier(0);

    f32x16 o0 = 0.0f, o1 = 0.0f;
    float m = -INFINITY, l = 0.0f;

    // ---- hot loop: tiles 0..nt-2 (mask-free) ----
#pragma unroll 1
    for (int t = 0; t < nt - 1; ++t) {
        attn_tile_r<false>(t * 64, kf, vb, qf, o0, o1, m, l, qrow, hi);
        asm volatile("s_waitcnt lgkmcnt(0) vmcnt(0)" ::: "memory");
        __builtin_amdgcn_s_barrier();
        __builtin_amdgcn_sched_barrier(0);
        if (t + 2 < nt) {
            short* Kso  = (t & 1) ? KsB  : KsA;     // buf[t&1] (fully consumed)
            short* Vtso = (t & 1) ? VtsB : VtsA;
            ISSUE_TILE(Kso, Vtso, (t + 2) * 64);
        }
        const short* Ksn  = (t & 1) ? KsA  : KsB;   // buf[(t+1)&1]
        const short* Vtsn = (t & 1) ? VtsA : VtsB;
        read_frags(Ksn, Vtsn, l31, hi, kf, vb);
        __builtin_amdgcn_sched_barrier(0);
    }

    // ---- peeled diagonal tile ----
    attn_tile_r<true>((nt - 1) * 64, kf, vb, qf, o0, o1, m, l, qrow, hi);
#undef ISSUE_TILE

    const float lt = l + __shfl_xor(l, 32, 64);   // deferred hi-pair sum
    const float il = 1.0f / lt;
#pragma unroll
    for (int r = 0; r < 16; ++r) {
        const int cr = (r & 3) + 8 * (r >> 2) + 4 * hi;
        const float s = __shfl(il, cr, 64);
        const size_t row = (size_t)(q0w + cr) * 1024;
        Op[row + l31]      = f2bfs(o0[r] * s);
        Op[row + 32 + l31] = f2bfs(o1[r] * s);
    }
}

// ---------------------------------------------------------------------------
extern "C" void kernel_launch(void* const* d_in, const int* in_sizes, int n_in,
                              void* d_out, int out_size, void* d_ws, size_t ws_size,
                              hipStream_t stream) {
    const float* x  = (const float*)d_in[0];
    const float* Wq = (const float*)d_in[1];
    const float* Wk = (const float*)d_in[2];
    const float* Wv = (const float*)d_in[3];
    const float* Wo = (const float*)d_in[4];

    short* wb  = (short*)d_ws;                 // 4 x 1M shorts (8 MB)
    short* Qw  = wb + (size_t)4 * 1048576;     // 8 MB (attn out aliases this)
    short* Kw  = Qw + (size_t)4194304;         // 8 MB
    short* Vtw = Kw + (size_t)4194304;         // 8 MB  (VtG[1024][4096])
    short* xb  = (short*)d_out;                // bf16 x lives in d_out[0:8MB]

    convert_kernel<<<4096, 256, 0, stream>>>(x, Wq, Wk, Wv, Wo, xb, wb);
    gemm_qkv_kernel<<<dim3(32, 24), 256, 0, stream>>>(xb, wb, Qw, Kw, Vtw);
    attn_kernel<<<1024, 128, 0, stream>>>(Qw, Kw, Vtw, Qw);
    gemm_wo_kernel<<<dim3(64, 8), 256, 0, stream>>>(Qw, wb + (size_t)3 * 1048576, (float*)d_out);
}